// Round 14
// baseline (811.823 us; speedup 1.0000x reference)
//
#include <hip/hip_runtime.h>
#include <math.h>

#define NN 10000           // nodes
#define NB 4               // batch
#define NE 160000          // edges
#define DM 256             // model dim
#define MR (NB * NN)       // 40000 flattened rows
#define LN_EPS 1e-5f
#define PCH 40             // pool node chunk
#define NCH (NN / PCH)     // 250
#define CCH 100            // colsum chunk

typedef __attribute__((ext_vector_type(8))) short short8;
typedef __attribute__((ext_vector_type(4))) float floatx4;
typedef __attribute__((ext_vector_type(2))) float f32x2;

// ---------------- helpers ----------------

__device__ inline float bf2f(unsigned short u) {
    unsigned int x = ((unsigned int)u) << 16;
    float f;
    __builtin_memcpy(&f, &x, 4);
    return f;
}

__device__ inline unsigned short f2bf(float f) {
    unsigned int x;
    __builtin_memcpy(&x, &f, 4);
    unsigned int r = x + 0x7FFFu + ((x >> 16) & 1u);
    return (unsigned short)(r >> 16);
}

__device__ inline float gelu_exact(float x) {
    return 0.5f * x * (1.0f + erff(x * 0.70710678118654752f));
}

__device__ inline float waveAllReduce(float v) {
#pragma unroll
    for (int off = 32; off > 0; off >>= 1) v += __shfl_xor(v, off, 64);
    return v;
}

// reduce over the 16-lane group sharing the same (lane>>4)
__device__ inline float group16Reduce(float v) {
#pragma unroll
    for (int off = 8; off > 0; off >>= 1) v += __shfl_xor(v, off, 64);
    return v;
}

// async global->LDS, 16B per lane. LDS dest must be wave-uniform + lane*16 (it is).
__device__ inline void gld16(const unsigned short* g, unsigned short* l) {
    __builtin_amdgcn_global_load_lds((const __attribute__((address_space(1))) void*)g,
                                     (__attribute__((address_space(3))) void*)l, 16, 0, 0);
}

// ---------------- utility kernels ----------------

__global__ void zero_i32_kernel(int* p, int n) {
    int i = blockIdx.x * 256 + threadIdx.x;
    if (i < n) p[i] = 0;
}

__global__ void cvt_bf16_kernel(const float* __restrict__ in, unsigned short* __restrict__ out, int n) {
    int i = blockIdx.x * 256 + threadIdx.x;
    if (i < n) out[i] = f2bf(in[i]);
}

// batched weight transpose+convert: Wt[n*K+k] = bf16(W[k*N+n])
struct TD { const float* src; unsigned short* dst; int K; int N; };
struct TDs { TD d[11]; };

__global__ void transpose_all_kernel(TDs tds) {
    TD t = tds.d[blockIdx.y];
    int idx = blockIdx.x * 256 + threadIdx.x;
    int total = t.K * t.N;
    if (idx < total) {
        int n = idx / t.K;
        int k = idx - n * t.K;
        t.dst[idx] = f2bf(t.src[(size_t)k * t.N + n]);
    }
}

// ---------------- CSR build ----------------

__global__ void hist_kernel(const int* __restrict__ dst, int* __restrict__ counts, int e) {
    int i = blockIdx.x * 256 + threadIdx.x;
    if (i < e) atomicAdd(&counts[dst[i]], 1);
}

__global__ __launch_bounds__(256) void scan_kernel(const int* __restrict__ counts,
                                                   int* __restrict__ row_ptr,
                                                   int* __restrict__ fill_pos, int n) {
    __shared__ int sums[256];
    int tid = threadIdx.x;
    int chunk = (n + 255) / 256;
    int s0 = tid * chunk;
    int s1 = min(n, s0 + chunk);
    int local = 0;
    for (int i = s0; i < s1; i++) local += counts[i];
    sums[tid] = local;
    __syncthreads();
    for (int off = 1; off < 256; off <<= 1) {
        int v = (tid >= off) ? sums[tid - off] : 0;
        __syncthreads();
        sums[tid] += v;
        __syncthreads();
    }
    int base = (tid == 0) ? 0 : sums[tid - 1];
    for (int i = s0; i < s1; i++) {
        row_ptr[i] = base;
        fill_pos[i] = base;
        base += counts[i];
    }
    if (tid == 255) row_ptr[n] = sums[255];
}

// stores PRE-SCALED byte offsets into f32 node-major sup: src * (NB*DM*4) = src*4096
__global__ void fill_kernel(const int* __restrict__ src, const int* __restrict__ dst,
                            int* __restrict__ fill_pos, int* __restrict__ csr_boff, int e) {
    int i = blockIdx.x * 256 + threadIdx.x;
    if (i < e) {
        int p = atomicAdd(&fill_pos[dst[i]], 1);
        csr_boff[p] = src[i] * (NB * DM * 4);
    }
}

// ---------------- MFMA GEMM ----------------
// C = act(A[MxK]bf16 @ B[KxN] + bias), B transposed bf16 as Bt[N][K].
// BM=64, block 256 = 4 waves (2x2), wave tile 32 x (BN/2).
// Compile-time K, double-buffered LDS, one barrier per K-iter.
// CM: 0 = f32 row-major, 1 = bf16 row-major, 3 = f32 node-major [n][b*DM+col]
// act: 0 none, 1 relu

template <int BN, int CM, int K>
__global__ __launch_bounds__(256) void mfma_gemm_kernel(
    const unsigned short* __restrict__ A, const unsigned short* __restrict__ Bt,
    const float* __restrict__ bias, void* __restrict__ Cp, int N, int act) {
    constexpr int NBF = BN / 32;
    constexpr int NI = K / 32;
    __shared__ unsigned short AsL[2][4 * 64 * 8];
    __shared__ unsigned short BsL[2][(BN / 16) * 64 * 8];

    const int tid = threadIdx.x;
    const int w = tid >> 6, l = tid & 63;
    const int wm = w >> 1, wn = w & 1;
    const int bm0 = blockIdx.y * 64;
    const int bn0 = blockIdx.x * BN;
    const int lm = l & 15, lq = l >> 4;

    floatx4 acc[2][NBF];
#pragma unroll
    for (int mi = 0; mi < 2; mi++)
#pragma unroll
        for (int ni = 0; ni < NBF; ni++) acc[mi][ni] = (floatx4){0.f, 0.f, 0.f, 0.f};

    const int a_row = bm0 + (tid >> 6) * 16 + (l & 15);
    const int s_kc = (l >> 4) * 8;
    // B staging coords per chunk
    int b_rown[BN / 64], b_kc[BN / 64];
#pragma unroll
    for (int cc = 0; cc < BN / 64; cc++) {
        int c = tid + cc * 256;
        b_rown[cc] = bn0 + (c >> 6) * 16 + (c & 15);
        b_kc[cc] = ((c & 63) >> 4) * 8;
    }

    // stage k-iter 0 into buf 0
    gld16(&A[(size_t)a_row * K + s_kc], &AsL[0][tid * 8]);
#pragma unroll
    for (int cc = 0; cc < BN / 64; cc++) {
        int c = tid + cc * 256;
        gld16(&Bt[(size_t)b_rown[cc] * K + b_kc[cc]], &BsL[0][c * 8]);
    }

#pragma unroll
    for (int i = 0; i < NI; i++) {
        const int buf = i & 1;
        __syncthreads();   // waits staging of buf i and prior reads of buf^1
        if (i + 1 < NI) {
            int k0 = (i + 1) * 32;
            gld16(&A[(size_t)a_row * K + k0 + s_kc], &AsL[buf ^ 1][tid * 8]);
#pragma unroll
            for (int cc = 0; cc < BN / 64; cc++) {
                int c = tid + cc * 256;
                gld16(&Bt[(size_t)b_rown[cc] * K + k0 + b_kc[cc]], &BsL[buf ^ 1][c * 8]);
            }
        }
        short8 af[2], bfv[NBF];
#pragma unroll
        for (int mi = 0; mi < 2; mi++) af[mi] = *(short8*)&AsL[buf][((wm * 2 + mi) * 64 + l) * 8];
#pragma unroll
        for (int ni = 0; ni < NBF; ni++) bfv[ni] = *(short8*)&BsL[buf][((wn * NBF + ni) * 64 + l) * 8];
#pragma unroll
        for (int mi = 0; mi < 2; mi++)
#pragma unroll
            for (int ni = 0; ni < NBF; ni++)
                acc[mi][ni] = __builtin_amdgcn_mfma_f32_16x16x32_bf16(af[mi], bfv[ni], acc[mi][ni], 0, 0, 0);
    }

#pragma unroll
    for (int ni = 0; ni < NBF; ni++) {
        int col = bn0 + (wn * NBF + ni) * 16 + lm;
        float bv = bias ? bias[col] : 0.0f;
#pragma unroll
        for (int mi = 0; mi < 2; mi++) {
            int row0 = bm0 + (wm * 2 + mi) * 16 + lq * 4;
#pragma unroll
            for (int r = 0; r < 4; r++) {
                int row = row0 + r;
                float v = acc[mi][ni][r] + bv;
                if (act == 1) v = fmaxf(v, 0.0f);
                if (CM == 0) {
                    ((float*)Cp)[(size_t)row * N + col] = v;
                } else if (CM == 1) {
                    ((unsigned short*)Cp)[(size_t)row * N + col] = f2bf(v);
                } else {
                    int bb = row / NN;
                    int nn = row - bb * NN;
                    ((float*)Cp)[(size_t)nn * (NB * DM) + bb * DM + col] = v;
                }
            }
        }
    }
}

// ---------------- fused GEMM + residual + LayerNorm ----------------
// out16 = LN( x1 + (A @ fW2 + fb2) ), all rows of N=256 owned by one block.
// BM=64, BN=256 (NBF=8), K=256. Grid = MR/64.

__global__ __launch_bounds__(256) void gemm_ln_kernel(
    const unsigned short* __restrict__ A,   // h1 [MR][256] bf16
    const unsigned short* __restrict__ Bt,  // fW2t [256][256] bf16
    const float* __restrict__ bias,         // fb2
    const unsigned short* __restrict__ x1,  // b16 [MR][256]
    const float* __restrict__ g, const float* __restrict__ bt,
    unsigned short* __restrict__ out16) {
    constexpr int K = 256, NBF = 8, NI = K / 32;
    __shared__ unsigned short AsL[2][4 * 64 * 8];
    __shared__ unsigned short BsL[2][16 * 64 * 8];
    __shared__ float rs[2][64], rq[2][64];

    const int tid = threadIdx.x;
    const int w = tid >> 6, l = tid & 63;
    const int wm = w >> 1, wn = w & 1;
    const int bm0 = blockIdx.x * 64;
    const int lm = l & 15, lq = l >> 4;

    floatx4 acc[2][NBF];
#pragma unroll
    for (int mi = 0; mi < 2; mi++)
#pragma unroll
        for (int ni = 0; ni < NBF; ni++) acc[mi][ni] = (floatx4){0.f, 0.f, 0.f, 0.f};

    const int a_row = bm0 + (tid >> 6) * 16 + (l & 15);
    const int s_kc = (l >> 4) * 8;
    int b_rown[4], b_kc[4];
#pragma unroll
    for (int cc = 0; cc < 4; cc++) {
        int c = tid + cc * 256;
        b_rown[cc] = (c >> 6) * 16 + (c & 15);
        b_kc[cc] = ((c & 63) >> 4) * 8;
    }

    gld16(&A[(size_t)a_row * K + s_kc], &AsL[0][tid * 8]);
#pragma unroll
    for (int cc = 0; cc < 4; cc++) {
        int c = tid + cc * 256;
        gld16(&Bt[(size_t)b_rown[cc] * K + b_kc[cc]], &BsL[0][c * 8]);
    }

#pragma unroll
    for (int i = 0; i < NI; i++) {
        const int buf = i & 1;
        __syncthreads();
        if (i + 1 < NI) {
            int k0 = (i + 1) * 32;
            gld16(&A[(size_t)a_row * K + k0 + s_kc], &AsL[buf ^ 1][tid * 8]);
#pragma unroll
            for (int cc = 0; cc < 4; cc++) {
                int c = tid + cc * 256;
                gld16(&Bt[(size_t)b_rown[cc] * K + k0 + b_kc[cc]], &BsL[buf ^ 1][c * 8]);
            }
        }
        short8 af[2], bfv[NBF];
#pragma unroll
        for (int mi = 0; mi < 2; mi++) af[mi] = *(short8*)&AsL[buf][((wm * 2 + mi) * 64 + l) * 8];
#pragma unroll
        for (int ni = 0; ni < NBF; ni++) bfv[ni] = *(short8*)&BsL[buf][((wn * NBF + ni) * 64 + l) * 8];
#pragma unroll
        for (int mi = 0; mi < 2; mi++)
#pragma unroll
            for (int ni = 0; ni < NBF; ni++)
                acc[mi][ni] = __builtin_amdgcn_mfma_f32_16x16x32_bf16(af[mi], bfv[ni], acc[mi][ni], 0, 0, 0);
    }

    // ---- epilogue: y = x1 + (acc + bias); row-wise LN over 256 cols ----
    float fb[NBF], gv[NBF], bv[NBF];
#pragma unroll
    for (int ni = 0; ni < NBF; ni++) {
        int col = (wn * NBF + ni) * 16 + lm;
        fb[ni] = bias[col];
        gv[ni] = g[col];
        bv[ni] = bt[col];
    }
    float psum[2][4], psq[2][4];
#pragma unroll
    for (int mi = 0; mi < 2; mi++)
#pragma unroll
        for (int r = 0; r < 4; r++) { psum[mi][r] = 0.f; psq[mi][r] = 0.f; }

#pragma unroll
    for (int mi = 0; mi < 2; mi++) {
        int row0 = bm0 + (wm * 2 + mi) * 16 + lq * 4;
#pragma unroll
        for (int r = 0; r < 4; r++) {
#pragma unroll
            for (int ni = 0; ni < NBF; ni++) {
                int col = (wn * NBF + ni) * 16 + lm;
                float y = bf2f(x1[(size_t)(row0 + r) * DM + col]) + acc[mi][ni][r] + fb[ni];
                acc[mi][ni][r] = y;   // reuse acc to hold y
                psum[mi][r] += y;
                psq[mi][r] += y * y;
            }
        }
    }
#pragma unroll
    for (int mi = 0; mi < 2; mi++)
#pragma unroll
        for (int r = 0; r < 4; r++) {
            float s = group16Reduce(psum[mi][r]);
            float q = group16Reduce(psq[mi][r]);
            if (lm == 0) {
                int rl = (wm * 2 + mi) * 16 + lq * 4 + r;
                rs[wn][rl] = s;
                rq[wn][rl] = q;
            }
        }
    __syncthreads();
#pragma unroll
    for (int mi = 0; mi < 2; mi++) {
        int row0 = bm0 + (wm * 2 + mi) * 16 + lq * 4;
#pragma unroll
        for (int r = 0; r < 4; r++) {
            int rl = (wm * 2 + mi) * 16 + lq * 4 + r;
            float s = rs[0][rl] + rs[1][rl];
            float q = rq[0][rl] + rq[1][rl];
            float mean = s * (1.0f / 256.0f);
            float var = q * (1.0f / 256.0f) - mean * mean;
            float rstd = rsqrtf(var + LN_EPS);
#pragma unroll
            for (int ni = 0; ni < NBF; ni++) {
                int col = (wn * NBF + ni) * 16 + lm;
                out16[(size_t)(row0 + r) * DM + col] =
                    f2bf((acc[mi][ni][r] - mean) * rstd * gv[ni] + bv[ni]);
            }
        }
    }
}

// ---------------- GCN aggregation (XCD-affinity slices, f32 sup) ----------------
// sup node-major FP32 [NN][NB*DM] (4096B/node). Slice = blockIdx&7 covers 512B
// (128 f32 dims); round-robin block->XCD dispatch keeps each slice mostly
// L2-resident (40MB/8 = 5MB vs 4MB L2; ~20% LLC spill). Wave = node (uniform
// degree), lane = 2 f32 dims (dwordx2 8B). Inner loop: scalar offset add +
// loadx2 + ONE v_pk_add_f32 -> 1/3 the unpack VALU of the bf16 variant.
// csr holds PRE-SCALED byte offsets (src*4096).

__global__ __launch_bounds__(256) void agg_kernel(const float* __restrict__ sup,
                                                  const int* __restrict__ row_ptr,
                                                  const int* __restrict__ csr_boff,
                                                  const float* __restrict__ bias,
                                                  unsigned short* __restrict__ out) {
    const char* supc = (const char*)sup;
    int slice = blockIdx.x & 7;
    int grp = blockIdx.x >> 3;                 // grid = (NN/4)*8 = 20000
    int w = threadIdx.x >> 6, l = threadIdx.x & 63;
    int n = grp * 4 + w;
    int s = __builtin_amdgcn_readfirstlane(row_ptr[n]);
    int e = __builtin_amdgcn_readfirstlane(row_ptr[n + 1]);
    const int lane_off = slice * 512 + l * 8;  // byte offset within 4096B node row
    f32x2 acc = {0.f, 0.f};
    int j = s;
    for (; j + 8 <= e; j += 8) {
        int off[8];
#pragma unroll
        for (int k = 0; k < 8; k++) off[k] = csr_boff[j + k];   // uniform -> s_load
        f32x2 v[8];
#pragma unroll
        for (int k = 0; k < 8; k++)
            v[k] = *(const f32x2*)(supc + (unsigned)(off[k] + lane_off));
#pragma unroll
        for (int k = 0; k < 8; k++) acc += v[k];
    }
    for (; j < e; j++) {
        f32x2 v = *(const f32x2*)(supc + (unsigned)(csr_boff[j] + lane_off));
        acc += v;
    }
    int gdim = slice * 128 + l * 2;    // packed dim in [0,1024)
    int b = gdim >> 8;
    int d = gdim & 255;
    float2 bv = *(const float2*)&bias[d];
    ushort2 o;
    o.x = f2bf(gelu_exact(acc[0] + bv.x));
    o.y = f2bf(gelu_exact(acc[1] + bv.y));
    *(ushort2*)&out[((size_t)b * NN + n) * DM + d] = o;
}

// ---------------- fused attention pooling ----------------
// Grid (NCH, NB). MODE 0: s = tanh(xW)u inline. MODE 1: s = x.r (r from global).
// Online-softmax partials (m, l, weighted-sum vec) per chunk.

template <int MODE>
__global__ __launch_bounds__(256) void attn_pool_kernel(const unsigned short* __restrict__ x16,
                                                        const float* __restrict__ W,
                                                        const float* __restrict__ u,
                                                        const float* __restrict__ r_in,
                                                        float* __restrict__ pm,
                                                        float* __restrict__ pl,
                                                        float* __restrict__ pv) {
    int c = blockIdx.x, b = blockIdx.y;
    int tid = threadIdx.x, w = tid >> 6, l = tid & 63;
    float4 rv = {0, 0, 0, 0};
    float u0[8];
    if (MODE == 1) {
        rv = *(const float4*)&r_in[b * DM + l * 4];
    } else {
#pragma unroll
        for (int j = 0; j < 8; j++) u0[j] = u[j];
    }
    int n0 = c * PCH;
    float m = -INFINITY, L = 0.0f;
    float v0 = 0.f, v1 = 0.f, v2 = 0.f, v3 = 0.f;
    for (int n = n0 + w; n < n0 + PCH; n += 4) {
        ushort4 xb = *(const ushort4*)&x16[((size_t)b * NN + n) * DM + l * 4];
        float x0 = bf2f(xb.x), x1 = bf2f(xb.y), x2 = bf2f(xb.z), x3 = bf2f(xb.w);
        float s;
        if (MODE == 1) {
            s = x0 * rv.x + x1 * rv.y + x2 * rv.z + x3 * rv.w;
            s = waveAllReduce(s);
        } else {
            const float4* Wv = (const float4*)W;
            int d0 = l * 4;
            float xs[4] = {x0, x1, x2, x3};
            float t[8] = {0, 0, 0, 0, 0, 0, 0, 0};
#pragma unroll
            for (int dd = 0; dd < 4; dd++) {
                float4 w0 = Wv[(d0 + dd) * 2 + 0];
                float4 w1 = Wv[(d0 + dd) * 2 + 1];
                t[0] += xs[dd] * w0.x; t[1] += xs[dd] * w0.y; t[2] += xs[dd] * w0.z; t[3] += xs[dd] * w0.w;
                t[4] += xs[dd] * w1.x; t[5] += xs[dd] * w1.y; t[6] += xs[dd] * w1.z; t[7] += xs[dd] * w1.w;
            }
#pragma unroll
            for (int jj = 0; jj < 8; jj++) t[jj] = waveAllReduce(t[jj]);
            s = 0.f;
#pragma unroll
            for (int jj = 0; jj < 8; jj++) s += tanhf(t[jj]) * u0[jj];
        }
        if (s > m) {  // wave-uniform branch
            float sc = __expf(m - s);
            L *= sc; v0 *= sc; v1 *= sc; v2 *= sc; v3 *= sc;
            m = s;
        }
        float wgt = __expf(s - m);
        L += wgt;
        v0 += wgt * x0; v1 += wgt * x1; v2 += wgt * x2; v3 += wgt * x3;
    }
    __shared__ float sm[4], sl[4];
    __shared__ float sv[4][DM];
    if (l == 0) { sm[w] = m; sl[w] = L; }
    float4 vv = {v0, v1, v2, v3};
    *(float4*)&sv[w][l * 4] = vv;
    __syncthreads();
    int d = tid;
    float M = fmaxf(fmaxf(sm[0], sm[1]), fmaxf(sm[2], sm[3]));
    float e0 = __expf(sm[0] - M), e1 = __expf(sm[1] - M);
    float e2 = __expf(sm[2] - M), e3 = __expf(sm[3] - M);
    float Lt = e0 * sl[0] + e1 * sl[1] + e2 * sl[2] + e3 * sl[3];
    float vd = e0 * sv[0][d] + e1 * sv[1][d] + e2 * sv[2][d] + e3 * sv[3][d];
    pv[((size_t)b * NCH + c) * DM + d] = vd;
    if (d == 0) {
        pm[b * NCH + c] = M;
        pl[b * NCH + c] = Lt;
    }
}

// one block per batch; strided parallel reductions over NCH chunks.
__global__ __launch_bounds__(256) void attn_combine_kernel(const float* __restrict__ pm,
                                                           const float* __restrict__ pl,
                                                           const float* __restrict__ pv,
                                                           float* __restrict__ r) {
    int b = blockIdx.x, tid = threadIdx.x;
    __shared__ float red[256];
    __shared__ float se[NCH];
    float mv = -INFINITY;
    for (int c = tid; c < NCH; c += 256) mv = fmaxf(mv, pm[b * NCH + c]);
    red[tid] = mv;
    __syncthreads();
    for (int off = 128; off > 0; off >>= 1) {
        if (tid < off) red[tid] = fmaxf(red[tid], red[tid + off]);
        __syncthreads();
    }
    float M = red[0];
    __syncthreads();
    float lsum = 0.0f;
    for (int c = tid; c < NCH; c += 256) {
        float e = __expf(pm[b * NCH + c] - M);
        se[c] = e;
        lsum += e * pl[b * NCH + c];
    }
    red[tid] = lsum;
    __syncthreads();
    for (int off = 128; off > 0; off >>= 1) {
        if (tid < off) red[tid] += red[tid + off];
        __syncthreads();
    }
    float L = red[0];
    __syncthreads();
    float acc = 0.0f;
    for (int c = 0; c < NCH; c++) acc += se[c] * pv[((size_t)b * NCH + c) * DM + tid];
    r[b * DM + tid] = acc / L;
}

// ---------------- LayerNorm (residual broadcast) ----------------

// out16 = LN(x16 + r[b])
__global__ __launch_bounds__(256) void ln_bcast_kernel(const unsigned short* __restrict__ x16,
                                                       const float* __restrict__ r,
                                                       const float* __restrict__ g,
                                                       const float* __restrict__ bt,
                                                       unsigned short* __restrict__ out16) {
    int l = threadIdx.x & 63, w = threadIdx.x >> 6;
    int row = blockIdx.x * 4 + w;
    int b = row / NN;
    ushort4 xb = *(const ushort4*)&x16[(size_t)row * DM + l * 4];
    float4 rv = *(const float4*)(r + (size_t)b * DM + l * 4);
    float4 y;
    y.x = bf2f(xb.x) + rv.x; y.y = bf2f(xb.y) + rv.y;
    y.z = bf2f(xb.z) + rv.z; y.w = bf2f(xb.w) + rv.w;
    float s = y.x + y.y + y.z + y.w;
    float sq = y.x * y.x + y.y * y.y + y.z * y.z + y.w * y.w;
    s = waveAllReduce(s);
    sq = waveAllReduce(sq);
    float mean = s * (1.0f / 256.0f);
    float var = sq * (1.0f / 256.0f) - mean * mean;
    float rstd = rsqrtf(var + LN_EPS);
    float4 gv = *(const float4*)(g + l * 4);
    float4 bv = *(const float4*)(bt + l * 4);
    ushort4 o;
    o.x = f2bf((y.x - mean) * rstd * gv.x + bv.x);
    o.y = f2bf((y.y - mean) * rstd * gv.y + bv.y);
    o.z = f2bf((y.z - mean) * rstd * gv.z + bv.z);
    o.w = f2bf((y.w - mean) * rstd * gv.w + bv.w);
    *(ushort4*)&out16[(size_t)row * DM + l * 4] = o;
}

// ---------------- final projection ----------------

// partial column sums (no atomics): pcol[(b*100+c)*DM + d]
__global__ __launch_bounds__(256) void colsum_kernel(const unsigned short* __restrict__ x16,
                                                     float* __restrict__ pcol) {
    int b = blockIdx.y, c = blockIdx.x, d = threadIdx.x;
    int n0 = c * CCH, n1 = n0 + CCH;
    float acc = 0.0f;
    for (int n = n0; n < n1; n++) acc += bf2f(x16[((size_t)b * NN + n) * DM + d]);
    pcol[((size_t)b * (NN / CCH) + c) * DM + d] = acc;
}

__global__ __launch_bounds__(256) void final_kernel(const float* __restrict__ pcol,
                                                    const float* __restrict__ fcW,
                                                    const float* __restrict__ fcb,
                                                    float* __restrict__ out) {
    int b = blockIdx.x, d = threadIdx.x;
    __shared__ float sx[DM];
    float acc = 0.0f;
    for (int c = 0; c < NN / CCH; c++) acc += pcol[((size_t)b * (NN / CCH) + c) * DM + d];
    sx[d] = acc;
    __syncthreads();
    if (d < 10) {
        float o = 0.0f;
        for (int k = 0; k < DM; k++) o += sx[k] * fcW[k * 10 + d];
        out[b * 10 + d] = o * (1.0f / NN) + fcb[d];
    }
}

// ---------------- launch ----------------

extern "C" void kernel_launch(void* const* d_in, const int* in_sizes, int n_in,
                              void* d_out, int out_size, void* d_ws, size_t ws_size,
                              hipStream_t stream) {
    const float* x_in    = (const float*)d_in[0];
    const int*   src     = (const int*)d_in[1];
    const int*   dst     = (const int*)d_in[2];
    const float* W_conv0 = (const float*)d_in[3];
    const float* b_conv0 = (const float*)d_in[4];
    const float* W_convs = (const float*)d_in[5];
    const float* b_convs = (const float*)d_in[6];
    const float* mW1 = (const float*)d_in[7];
    const float* mb1 = (const float*)d_in[8];
    const float* mW2 = (const float*)d_in[9];
    const float* mb2 = (const float*)d_in[10];
    const float* mW3 = (const float*)d_in[11];
    const float* mb3 = (const float*)d_in[12];
    const float* ln1_g = (const float*)d_in[13];
    const float* ln1_b = (const float*)d_in[14];
    const float* ln2_g = (const float*)d_in[15];
    const float* ln2_b = (const float*)d_in[16];
    const float* attnW = (const float*)d_in[17];
    const float* attnu = (const float*)d_in[18];
    const float* fW1 = (const float*)d_in[19];
    const float* fb1 = (const float*)d_in[20];
    const float* fW2 = (const float*)d_in[21];
    const float* fb2 = (const float*)d_in[22];
    const float* fcW = (const float*)d_in[23];
    const float* fcb = (const float*)d_in[24];
    float* out = (float*)d_out;

    // ---- workspace carve ----
    char* p = (char*)d_ws;
    auto alloc = [&](size_t bytes) { char* q = p; p += (bytes + 255) & ~(size_t)255; return q; };
    float* supf = (float*)alloc((size_t)MR * DM * 4);                     // node-major sup (f32)
    unsigned short* h16   = (unsigned short*)alloc((size_t)MR * DM * 2);  // h1 bf16
    unsigned short* act16 = (unsigned short*)alloc((size_t)MR * DM * 2);  // x bf16
    unsigned short* b16   = (unsigned short*)alloc((size_t)MR * DM * 2);  // LN1 output
    unsigned short* t1    = (unsigned short*)alloc((size_t)MR * 128 * 2); // x_in bf16 / MLP mid
    unsigned short* t2    = (unsigned short*)alloc((size_t)MR * 64 * 2);
    unsigned short* wt    = (unsigned short*)alloc((size_t)548864 * 2);
    float* rbuf = (float*)alloc(NB * DM * 4);
    float* pm0  = (float*)alloc(NB * NCH * 4);
    float* pl0  = (float*)alloc(NB * NCH * 4);
    float* pv0  = (float*)alloc((size_t)NB * NCH * DM * 4);
    float* pcol = (float*)alloc((size_t)NB * (NN / CCH) * DM * 4);
    int* counts   = (int*)alloc(NN * 4);
    int* row_ptr  = (int*)alloc((NN + 1) * 4);
    int* fill_pos = (int*)alloc(NN * 4);
    int* csr_boff = (int*)alloc(NE * 4);

    unsigned short* Wt_conv0 = wt;                       // 256x128
    unsigned short* Wt_convs = Wt_conv0 + 32768;         // 3 x 256x256
    unsigned short* mW1t = Wt_convs + 196608;            // 128x256
    unsigned short* mW2t = mW1t + 32768;                 // 64x128
    unsigned short* mW3t = mW2t + 8192;                  // 256x64
    unsigned short* fW1t = mW3t + 16384;                 // 2 x 256x256
    unsigned short* fW2t = fW1t + 131072;                // 2 x 256x256

    const dim3 blk(256);

    // ---- CSR build (by dst) ----
    zero_i32_kernel<<<(NN + 255) / 256, blk, 0, stream>>>(counts, NN);
    hist_kernel<<<(NE + 255) / 256, blk, 0, stream>>>(dst, counts, NE);
    scan_kernel<<<1, blk, 0, stream>>>(counts, row_ptr, fill_pos, NN);
    fill_kernel<<<(NE + 255) / 256, blk, 0, stream>>>(src, dst, fill_pos, csr_boff, NE);

    // ---- weight transposes ----
    TDs tds;
    tds.d[0]  = {W_conv0, Wt_conv0, 128, 256};
    tds.d[1]  = {W_convs + 0 * 65536, Wt_convs + 0 * 65536, 256, 256};
    tds.d[2]  = {W_convs + 1 * 65536, Wt_convs + 1 * 65536, 256, 256};
    tds.d[3]  = {W_convs + 2 * 65536, Wt_convs + 2 * 65536, 256, 256};
    tds.d[4]  = {mW1, mW1t, 256, 128};
    tds.d[5]  = {mW2, mW2t, 128, 64};
    tds.d[6]  = {mW3, mW3t, 64, 256};
    tds.d[7]  = {fW1 + 0 * 65536, fW1t + 0 * 65536, 256, 256};
    tds.d[8]  = {fW1 + 1 * 65536, fW1t + 1 * 65536, 256, 256};
    tds.d[9]  = {fW2 + 0 * 65536, fW2t + 0 * 65536, 256, 256};
    tds.d[10] = {fW2 + 1 * 65536, fW2t + 1 * 65536, 256, 256};
    transpose_all_kernel<<<dim3(256, 11), blk, 0, stream>>>(tds);

    cvt_bf16_kernel<<<(MR * 128 + 255) / 256, blk, 0, stream>>>(x_in, t1, MR * 128);

    // ---- GCN layers (GEMM writes f32 node-major supf; agg emits row-major bf16) ----
    mfma_gemm_kernel<256, 3, 128><<<dim3(1, MR / 64), blk, 0, stream>>>(t1, Wt_conv0, nullptr, supf, 256, 0);
    agg_kernel<<<NN * 2, blk, 0, stream>>>(supf, row_ptr, csr_boff, b_conv0, act16);
    for (int i = 0; i < 3; i++) {
        mfma_gemm_kernel<256, 3, 256><<<dim3(1, MR / 64), blk, 0, stream>>>(act16, Wt_convs + (size_t)i * 65536, nullptr, supf, 256, 0);
        agg_kernel<<<NN * 2, blk, 0, stream>>>(supf, row_ptr, csr_boff, b_convs + (size_t)i * 256, act16);
    }

    // ---- MLP ----
    mfma_gemm_kernel<128, 1, 256><<<dim3(1, MR / 64), blk, 0, stream>>>(act16, mW1t, mb1, t1, 128, 1);
    mfma_gemm_kernel<64, 1, 128><<<dim3(1, MR / 64), blk, 0, stream>>>(t1, mW2t, mb2, t2, 64, 1);
    mfma_gemm_kernel<256, 1, 64><<<dim3(1, MR / 64), blk, 0, stream>>>(t2, mW3t, mb3, act16, 256, 0);

    // ---- 2 attention/FFN blocks; x bf16 in act16 ----
    const dim3 poolGrid(NCH, NB);
    for (int i = 0; i < 2; i++) {
        const float* Wp = attnW + (size_t)i * DM * 8;
        const float* up = attnu + (size_t)i * 8;
        attn_pool_kernel<0><<<poolGrid, blk, 0, stream>>>(act16, Wp, up, nullptr, pm0, pl0, pv0);
        attn_combine_kernel<<<NB, blk, 0, stream>>>(pm0, pl0, pv0, rbuf);
        for (int it = 0; it < 3; it++) {
            attn_pool_kernel<1><<<poolGrid, blk, 0, stream>>>(act16, nullptr, nullptr, rbuf, pm0, pl0, pv0);
            attn_combine_kernel<<<NB, blk, 0, stream>>>(pm0, pl0, pv0, rbuf);
        }
        // x1 = LN(x + r) -> b16
        ln_bcast_kernel<<<MR / 4, blk, 0, stream>>>(act16, rbuf, ln1_g + (size_t)i * DM,
                                                    ln1_b + (size_t)i * DM, b16);
        // h1 = relu(x1 @ fW1 + fb1) -> h16 (row-major bf16)
        mfma_gemm_kernel<256, 1, 256><<<dim3(1, MR / 64), blk, 0, stream>>>(b16, fW1t + (size_t)i * 65536,
                                                                            fb1 + (size_t)i * DM, h16, 256, 1);
        // x = LN(x1 + (h1 @ fW2 + fb2)) -> act16  (fused GEMM+residual+LN)
        gemm_ln_kernel<<<MR / 64, blk, 0, stream>>>(h16, fW2t + (size_t)i * 65536,
                                                    fb2 + (size_t)i * DM, b16,
                                                    ln2_g + (size_t)i * DM, ln2_b + (size_t)i * DM,
                                                    act16);
    }

    // ---- final: mean over nodes commutes with the linear layer ----
    colsum_kernel<<<dim3(NN / CCH, NB), blk, 0, stream>>>(act16, pcol);
    final_kernel<<<NB, blk, 0, stream>>>(pcol, fcW, fcb, out);
}

// Round 15
// 730.365 us; speedup vs baseline: 1.1115x; 1.1115x over previous
//
#include <hip/hip_runtime.h>
#include <math.h>

#define NN 10000           // nodes
#define NB 4               // batch
#define NE 160000          // edges
#define DM 256             // model dim
#define MR (NB * NN)       // 40000 flattened rows
#define LN_EPS 1e-5f
#define PCH 40             // pool node chunk
#define NCH (NN / PCH)     // 250
#define CCH 100            // colsum chunk

typedef __attribute__((ext_vector_type(8))) short short8;
typedef __attribute__((ext_vector_type(4))) float floatx4;
typedef __attribute__((ext_vector_type(2))) float f32x2;

// ---------------- helpers ----------------

__device__ inline float bf2f(unsigned short u) {
    unsigned int x = ((unsigned int)u) << 16;
    float f;
    __builtin_memcpy(&f, &x, 4);
    return f;
}

__device__ inline unsigned short f2bf(float f) {
    unsigned int x;
    __builtin_memcpy(&x, &f, 4);
    unsigned int r = x + 0x7FFFu + ((x >> 16) & 1u);
    return (unsigned short)(r >> 16);
}

__device__ inline float gelu_exact(float x) {
    return 0.5f * x * (1.0f + erff(x * 0.70710678118654752f));
}

__device__ inline float waveAllReduce(float v) {
#pragma unroll
    for (int off = 32; off > 0; off >>= 1) v += __shfl_xor(v, off, 64);
    return v;
}

// reduce over the 16-lane group sharing the same (lane>>4)
__device__ inline float group16Reduce(float v) {
#pragma unroll
    for (int off = 8; off > 0; off >>= 1) v += __shfl_xor(v, off, 64);
    return v;
}

// async global->LDS, 16B per lane. LDS dest must be wave-uniform + lane*16 (it is).
__device__ inline void gld16(const unsigned short* g, unsigned short* l) {
    __builtin_amdgcn_global_load_lds((const __attribute__((address_space(1))) void*)g,
                                     (__attribute__((address_space(3))) void*)l, 16, 0, 0);
}

// ---------------- utility kernels ----------------

__global__ void zero_i32_kernel(int* p, int n) {
    int i = blockIdx.x * 256 + threadIdx.x;
    if (i < n) p[i] = 0;
}

__global__ void cvt_bf16_kernel(const float* __restrict__ in, unsigned short* __restrict__ out, int n) {
    int i = blockIdx.x * 256 + threadIdx.x;
    if (i < n) out[i] = f2bf(in[i]);
}

// batched weight transpose+convert: Wt[n*K+k] = bf16(W[k*N+n])
struct TD { const float* src; unsigned short* dst; int K; int N; };
struct TDs { TD d[11]; };

__global__ void transpose_all_kernel(TDs tds) {
    TD t = tds.d[blockIdx.y];
    int idx = blockIdx.x * 256 + threadIdx.x;
    int total = t.K * t.N;
    if (idx < total) {
        int n = idx / t.K;
        int k = idx - n * t.K;
        t.dst[idx] = f2bf(t.src[(size_t)k * t.N + n]);
    }
}

// ---------------- CSR build ----------------

__global__ void hist_kernel(const int* __restrict__ dst, int* __restrict__ counts, int e) {
    int i = blockIdx.x * 256 + threadIdx.x;
    if (i < e) atomicAdd(&counts[dst[i]], 1);
}

__global__ __launch_bounds__(256) void scan_kernel(const int* __restrict__ counts,
                                                   int* __restrict__ row_ptr,
                                                   int* __restrict__ fill_pos, int n) {
    __shared__ int sums[256];
    int tid = threadIdx.x;
    int chunk = (n + 255) / 256;
    int s0 = tid * chunk;
    int s1 = min(n, s0 + chunk);
    int local = 0;
    for (int i = s0; i < s1; i++) local += counts[i];
    sums[tid] = local;
    __syncthreads();
    for (int off = 1; off < 256; off <<= 1) {
        int v = (tid >= off) ? sums[tid - off] : 0;
        __syncthreads();
        sums[tid] += v;
        __syncthreads();
    }
    int base = (tid == 0) ? 0 : sums[tid - 1];
    for (int i = s0; i < s1; i++) {
        row_ptr[i] = base;
        fill_pos[i] = base;
        base += counts[i];
    }
    if (tid == 255) row_ptr[n] = sums[255];
}

// stores PRE-SCALED byte offsets: src * (NB*DM*2) = src*2048
__global__ void fill_kernel(const int* __restrict__ src, const int* __restrict__ dst,
                            int* __restrict__ fill_pos, int* __restrict__ csr_boff, int e) {
    int i = blockIdx.x * 256 + threadIdx.x;
    if (i < e) {
        int p = atomicAdd(&fill_pos[dst[i]], 1);
        csr_boff[p] = src[i] * (NB * DM * 2);
    }
}

// ---------------- MFMA GEMM ----------------
// C = act(A[MxK]bf16 @ B[KxN] + bias), B transposed bf16 as Bt[N][K].
// BM=64, block 256 = 4 waves (2x2), wave tile 32 x (BN/2).
// Compile-time K, double-buffered LDS, one barrier per K-iter.
// CM: 0 = f32 row-major, 1 = bf16 row-major, 2 = bf16 node-major [n][b*DM+col]
// act: 0 none, 1 relu

template <int BN, int CM, int K>
__global__ __launch_bounds__(256) void mfma_gemm_kernel(
    const unsigned short* __restrict__ A, const unsigned short* __restrict__ Bt,
    const float* __restrict__ bias, void* __restrict__ Cp, int N, int act) {
    constexpr int NBF = BN / 32;
    constexpr int NI = K / 32;
    __shared__ unsigned short AsL[2][4 * 64 * 8];
    __shared__ unsigned short BsL[2][(BN / 16) * 64 * 8];

    const int tid = threadIdx.x;
    const int w = tid >> 6, l = tid & 63;
    const int wm = w >> 1, wn = w & 1;
    const int bm0 = blockIdx.y * 64;
    const int bn0 = blockIdx.x * BN;
    const int lm = l & 15, lq = l >> 4;

    floatx4 acc[2][NBF];
#pragma unroll
    for (int mi = 0; mi < 2; mi++)
#pragma unroll
        for (int ni = 0; ni < NBF; ni++) acc[mi][ni] = (floatx4){0.f, 0.f, 0.f, 0.f};

    const int a_row = bm0 + (tid >> 6) * 16 + (l & 15);
    const int s_kc = (l >> 4) * 8;
    // B staging coords per chunk
    int b_rown[BN / 64], b_kc[BN / 64];
#pragma unroll
    for (int cc = 0; cc < BN / 64; cc++) {
        int c = tid + cc * 256;
        b_rown[cc] = bn0 + (c >> 6) * 16 + (c & 15);
        b_kc[cc] = ((c & 63) >> 4) * 8;
    }

    // stage k-iter 0 into buf 0
    gld16(&A[(size_t)a_row * K + s_kc], &AsL[0][tid * 8]);
#pragma unroll
    for (int cc = 0; cc < BN / 64; cc++) {
        int c = tid + cc * 256;
        gld16(&Bt[(size_t)b_rown[cc] * K + b_kc[cc]], &BsL[0][c * 8]);
    }

#pragma unroll
    for (int i = 0; i < NI; i++) {
        const int buf = i & 1;
        __syncthreads();   // waits staging of buf i and prior reads of buf^1
        if (i + 1 < NI) {
            int k0 = (i + 1) * 32;
            gld16(&A[(size_t)a_row * K + k0 + s_kc], &AsL[buf ^ 1][tid * 8]);
#pragma unroll
            for (int cc = 0; cc < BN / 64; cc++) {
                int c = tid + cc * 256;
                gld16(&Bt[(size_t)b_rown[cc] * K + k0 + b_kc[cc]], &BsL[buf ^ 1][c * 8]);
            }
        }
        short8 af[2], bfv[NBF];
#pragma unroll
        for (int mi = 0; mi < 2; mi++) af[mi] = *(short8*)&AsL[buf][((wm * 2 + mi) * 64 + l) * 8];
#pragma unroll
        for (int ni = 0; ni < NBF; ni++) bfv[ni] = *(short8*)&BsL[buf][((wn * NBF + ni) * 64 + l) * 8];
#pragma unroll
        for (int mi = 0; mi < 2; mi++)
#pragma unroll
            for (int ni = 0; ni < NBF; ni++)
                acc[mi][ni] = __builtin_amdgcn_mfma_f32_16x16x32_bf16(af[mi], bfv[ni], acc[mi][ni], 0, 0, 0);
    }

#pragma unroll
    for (int ni = 0; ni < NBF; ni++) {
        int col = bn0 + (wn * NBF + ni) * 16 + lm;
        float bv = bias ? bias[col] : 0.0f;
#pragma unroll
        for (int mi = 0; mi < 2; mi++) {
            int row0 = bm0 + (wm * 2 + mi) * 16 + lq * 4;
#pragma unroll
            for (int r = 0; r < 4; r++) {
                int row = row0 + r;
                float v = acc[mi][ni][r] + bv;
                if (act == 1) v = fmaxf(v, 0.0f);
                if (CM == 0) {
                    ((float*)Cp)[(size_t)row * N + col] = v;
                } else if (CM == 1) {
                    ((unsigned short*)Cp)[(size_t)row * N + col] = f2bf(v);
                } else {
                    int bb = row / NN;
                    int nn = row - bb * NN;
                    ((unsigned short*)Cp)[(size_t)nn * (NB * DM) + bb * DM + col] = f2bf(v);
                }
            }
        }
    }
}

// ---------------- fused GEMM + residual + LayerNorm ----------------
// out16 = LN( x1 + (A @ fW2 + fb2) ), all rows of N=256 owned by one block.
// BM=64, BN=256 (NBF=8), K=256. Grid = MR/64.

__global__ __launch_bounds__(256) void gemm_ln_kernel(
    const unsigned short* __restrict__ A,   // h1 [MR][256] bf16
    const unsigned short* __restrict__ Bt,  // fW2t [256][256] bf16
    const float* __restrict__ bias,         // fb2
    const unsigned short* __restrict__ x1,  // b16 [MR][256]
    const float* __restrict__ g, const float* __restrict__ bt,
    unsigned short* __restrict__ out16) {
    constexpr int K = 256, NBF = 8, NI = K / 32;
    __shared__ unsigned short AsL[2][4 * 64 * 8];
    __shared__ unsigned short BsL[2][16 * 64 * 8];
    __shared__ float rs[2][64], rq[2][64];

    const int tid = threadIdx.x;
    const int w = tid >> 6, l = tid & 63;
    const int wm = w >> 1, wn = w & 1;
    const int bm0 = blockIdx.x * 64;
    const int lm = l & 15, lq = l >> 4;

    floatx4 acc[2][NBF];
#pragma unroll
    for (int mi = 0; mi < 2; mi++)
#pragma unroll
        for (int ni = 0; ni < NBF; ni++) acc[mi][ni] = (floatx4){0.f, 0.f, 0.f, 0.f};

    const int a_row = bm0 + (tid >> 6) * 16 + (l & 15);
    const int s_kc = (l >> 4) * 8;
    int b_rown[4], b_kc[4];
#pragma unroll
    for (int cc = 0; cc < 4; cc++) {
        int c = tid + cc * 256;
        b_rown[cc] = (c >> 6) * 16 + (c & 15);
        b_kc[cc] = ((c & 63) >> 4) * 8;
    }

    gld16(&A[(size_t)a_row * K + s_kc], &AsL[0][tid * 8]);
#pragma unroll
    for (int cc = 0; cc < 4; cc++) {
        int c = tid + cc * 256;
        gld16(&Bt[(size_t)b_rown[cc] * K + b_kc[cc]], &BsL[0][c * 8]);
    }

#pragma unroll
    for (int i = 0; i < NI; i++) {
        const int buf = i & 1;
        __syncthreads();
        if (i + 1 < NI) {
            int k0 = (i + 1) * 32;
            gld16(&A[(size_t)a_row * K + k0 + s_kc], &AsL[buf ^ 1][tid * 8]);
#pragma unroll
            for (int cc = 0; cc < 4; cc++) {
                int c = tid + cc * 256;
                gld16(&Bt[(size_t)b_rown[cc] * K + k0 + b_kc[cc]], &BsL[buf ^ 1][c * 8]);
            }
        }
        short8 af[2], bfv[NBF];
#pragma unroll
        for (int mi = 0; mi < 2; mi++) af[mi] = *(short8*)&AsL[buf][((wm * 2 + mi) * 64 + l) * 8];
#pragma unroll
        for (int ni = 0; ni < NBF; ni++) bfv[ni] = *(short8*)&BsL[buf][((wn * NBF + ni) * 64 + l) * 8];
#pragma unroll
        for (int mi = 0; mi < 2; mi++)
#pragma unroll
            for (int ni = 0; ni < NBF; ni++)
                acc[mi][ni] = __builtin_amdgcn_mfma_f32_16x16x32_bf16(af[mi], bfv[ni], acc[mi][ni], 0, 0, 0);
    }

    // ---- epilogue: y = x1 + (acc + bias); row-wise LN over 256 cols ----
    float fb[NBF], gv[NBF], bv[NBF];
#pragma unroll
    for (int ni = 0; ni < NBF; ni++) {
        int col = (wn * NBF + ni) * 16 + lm;
        fb[ni] = bias[col];
        gv[ni] = g[col];
        bv[ni] = bt[col];
    }
    float psum[2][4], psq[2][4];
#pragma unroll
    for (int mi = 0; mi < 2; mi++)
#pragma unroll
        for (int r = 0; r < 4; r++) { psum[mi][r] = 0.f; psq[mi][r] = 0.f; }

#pragma unroll
    for (int mi = 0; mi < 2; mi++) {
        int row0 = bm0 + (wm * 2 + mi) * 16 + lq * 4;
#pragma unroll
        for (int r = 0; r < 4; r++) {
#pragma unroll
            for (int ni = 0; ni < NBF; ni++) {
                int col = (wn * NBF + ni) * 16 + lm;
                float y = bf2f(x1[(size_t)(row0 + r) * DM + col]) + acc[mi][ni][r] + fb[ni];
                acc[mi][ni][r] = y;   // reuse acc to hold y
                psum[mi][r] += y;
                psq[mi][r] += y * y;
            }
        }
    }
#pragma unroll
    for (int mi = 0; mi < 2; mi++)
#pragma unroll
        for (int r = 0; r < 4; r++) {
            float s = group16Reduce(psum[mi][r]);
            float q = group16Reduce(psq[mi][r]);
            if (lm == 0) {
                int rl = (wm * 2 + mi) * 16 + lq * 4 + r;
                rs[wn][rl] = s;
                rq[wn][rl] = q;
            }
        }
    __syncthreads();
#pragma unroll
    for (int mi = 0; mi < 2; mi++) {
        int row0 = bm0 + (wm * 2 + mi) * 16 + lq * 4;
#pragma unroll
        for (int r = 0; r < 4; r++) {
            int rl = (wm * 2 + mi) * 16 + lq * 4 + r;
            float s = rs[0][rl] + rs[1][rl];
            float q = rq[0][rl] + rq[1][rl];
            float mean = s * (1.0f / 256.0f);
            float var = q * (1.0f / 256.0f) - mean * mean;
            float rstd = rsqrtf(var + LN_EPS);
#pragma unroll
            for (int ni = 0; ni < NBF; ni++) {
                int col = (wn * NBF + ni) * 16 + lm;
                out16[(size_t)(row0 + r) * DM + col] =
                    f2bf((acc[mi][ni][r] - mean) * rstd * gv[ni] + bv[ni]);
            }
        }
    }
}

// ---------------- GCN aggregation (XCD-affinity slices, lean VALU) ----------------
// sup node-major [NN][NB*DM] (2048B/node). Slice = blockIdx&7 covers 256B
// (128 dims); round-robin block->XCD dispatch keeps each slice L2-resident
// (20MB/8 = 2.5MB < 4MB). Wave = node (uniform degree, no divergence),
// lane = 2 dims (ushort2, 4B). csr holds PRE-SCALED byte offsets (src*2048);
// row bounds via readfirstlane -> edge offsets come in as s_loads.

__global__ __launch_bounds__(256) void agg_kernel(const unsigned short* __restrict__ sup,
                                                  const int* __restrict__ row_ptr,
                                                  const int* __restrict__ csr_boff,
                                                  const float* __restrict__ bias,
                                                  unsigned short* __restrict__ out) {
    const char* supc = (const char*)sup;
    int slice = blockIdx.x & 7;
    int grp = blockIdx.x >> 3;                 // grid = (NN/4)*8 = 20000
    int w = threadIdx.x >> 6, l = threadIdx.x & 63;
    int n = grp * 4 + w;
    int s = __builtin_amdgcn_readfirstlane(row_ptr[n]);
    int e = __builtin_amdgcn_readfirstlane(row_ptr[n + 1]);
    const int lane_off = slice * 256 + l * 4;  // byte offset within 2048B node row
    f32x2 acc = {0.f, 0.f};
    int j = s;
    for (; j + 8 <= e; j += 8) {
        int off[8];
#pragma unroll
        for (int k = 0; k < 8; k++) off[k] = csr_boff[j + k];   // uniform -> s_load
        unsigned int v[8];
#pragma unroll
        for (int k = 0; k < 8; k++)
            v[k] = *(const unsigned int*)(supc + (unsigned)(off[k] + lane_off));
#pragma unroll
        for (int k = 0; k < 8; k++) {
            unsigned int lo = v[k] << 16;
            unsigned int hi = v[k] & 0xFFFF0000u;
            float fx, fy;
            __builtin_memcpy(&fx, &lo, 4);
            __builtin_memcpy(&fy, &hi, 4);
            f32x2 t = {fx, fy};
            acc += t;
        }
    }
    for (; j < e; j++) {
        unsigned int v = *(const unsigned int*)(supc + (unsigned)(csr_boff[j] + lane_off));
        unsigned int lo = v << 16;
        unsigned int hi = v & 0xFFFF0000u;
        float fx, fy;
        __builtin_memcpy(&fx, &lo, 4);
        __builtin_memcpy(&fy, &hi, 4);
        f32x2 t = {fx, fy};
        acc += t;
    }
    int gdim = slice * 128 + l * 2;    // packed dim in [0,1024)
    int b = gdim >> 8;
    int d = gdim & 255;
    float2 bv = *(const float2*)&bias[d];
    ushort2 o;
    o.x = f2bf(gelu_exact(acc[0] + bv.x));
    o.y = f2bf(gelu_exact(acc[1] + bv.y));
    *(ushort2*)&out[((size_t)b * NN + n) * DM + d] = o;
}

// ---------------- fused attention pooling ----------------
// Grid (NCH, NB). MODE 0: s = tanh(xW)u inline. MODE 1: s = x.r (r from global).
// Online-softmax partials (m, l, weighted-sum vec) per chunk.

template <int MODE>
__global__ __launch_bounds__(256) void attn_pool_kernel(const unsigned short* __restrict__ x16,
                                                        const float* __restrict__ W,
                                                        const float* __restrict__ u,
                                                        const float* __restrict__ r_in,
                                                        float* __restrict__ pm,
                                                        float* __restrict__ pl,
                                                        float* __restrict__ pv) {
    int c = blockIdx.x, b = blockIdx.y;
    int tid = threadIdx.x, w = tid >> 6, l = tid & 63;
    float4 rv = {0, 0, 0, 0};
    float u0[8];
    if (MODE == 1) {
        rv = *(const float4*)&r_in[b * DM + l * 4];
    } else {
#pragma unroll
        for (int j = 0; j < 8; j++) u0[j] = u[j];
    }
    int n0 = c * PCH;
    float m = -INFINITY, L = 0.0f;
    float v0 = 0.f, v1 = 0.f, v2 = 0.f, v3 = 0.f;
    for (int n = n0 + w; n < n0 + PCH; n += 4) {
        ushort4 xb = *(const ushort4*)&x16[((size_t)b * NN + n) * DM + l * 4];
        float x0 = bf2f(xb.x), x1 = bf2f(xb.y), x2 = bf2f(xb.z), x3 = bf2f(xb.w);
        float s;
        if (MODE == 1) {
            s = x0 * rv.x + x1 * rv.y + x2 * rv.z + x3 * rv.w;
            s = waveAllReduce(s);
        } else {
            const float4* Wv = (const float4*)W;
            int d0 = l * 4;
            float xs[4] = {x0, x1, x2, x3};
            float t[8] = {0, 0, 0, 0, 0, 0, 0, 0};
#pragma unroll
            for (int dd = 0; dd < 4; dd++) {
                float4 w0 = Wv[(d0 + dd) * 2 + 0];
                float4 w1 = Wv[(d0 + dd) * 2 + 1];
                t[0] += xs[dd] * w0.x; t[1] += xs[dd] * w0.y; t[2] += xs[dd] * w0.z; t[3] += xs[dd] * w0.w;
                t[4] += xs[dd] * w1.x; t[5] += xs[dd] * w1.y; t[6] += xs[dd] * w1.z; t[7] += xs[dd] * w1.w;
            }
#pragma unroll
            for (int jj = 0; jj < 8; jj++) t[jj] = waveAllReduce(t[jj]);
            s = 0.f;
#pragma unroll
            for (int jj = 0; jj < 8; jj++) s += tanhf(t[jj]) * u0[jj];
        }
        if (s > m) {  // wave-uniform branch
            float sc = __expf(m - s);
            L *= sc; v0 *= sc; v1 *= sc; v2 *= sc; v3 *= sc;
            m = s;
        }
        float wgt = __expf(s - m);
        L += wgt;
        v0 += wgt * x0; v1 += wgt * x1; v2 += wgt * x2; v3 += wgt * x3;
    }
    __shared__ float sm[4], sl[4];
    __shared__ float sv[4][DM];
    if (l == 0) { sm[w] = m; sl[w] = L; }
    float4 vv = {v0, v1, v2, v3};
    *(float4*)&sv[w][l * 4] = vv;
    __syncthreads();
    int d = tid;
    float M = fmaxf(fmaxf(sm[0], sm[1]), fmaxf(sm[2], sm[3]));
    float e0 = __expf(sm[0] - M), e1 = __expf(sm[1] - M);
    float e2 = __expf(sm[2] - M), e3 = __expf(sm[3] - M);
    float Lt = e0 * sl[0] + e1 * sl[1] + e2 * sl[2] + e3 * sl[3];
    float vd = e0 * sv[0][d] + e1 * sv[1][d] + e2 * sv[2][d] + e3 * sv[3][d];
    pv[((size_t)b * NCH + c) * DM + d] = vd;
    if (d == 0) {
        pm[b * NCH + c] = M;
        pl[b * NCH + c] = Lt;
    }
}

// one block per batch; strided parallel reductions over NCH chunks.
__global__ __launch_bounds__(256) void attn_combine_kernel(const float* __restrict__ pm,
                                                           const float* __restrict__ pl,
                                                           const float* __restrict__ pv,
                                                           float* __restrict__ r) {
    int b = blockIdx.x, tid = threadIdx.x;
    __shared__ float red[256];
    __shared__ float se[NCH];
    float mv = -INFINITY;
    for (int c = tid; c < NCH; c += 256) mv = fmaxf(mv, pm[b * NCH + c]);
    red[tid] = mv;
    __syncthreads();
    for (int off = 128; off > 0; off >>= 1) {
        if (tid < off) red[tid] = fmaxf(red[tid], red[tid + off]);
        __syncthreads();
    }
    float M = red[0];
    __syncthreads();
    float lsum = 0.0f;
    for (int c = tid; c < NCH; c += 256) {
        float e = __expf(pm[b * NCH + c] - M);
        se[c] = e;
        lsum += e * pl[b * NCH + c];
    }
    red[tid] = lsum;
    __syncthreads();
    for (int off = 128; off > 0; off >>= 1) {
        if (tid < off) red[tid] += red[tid + off];
        __syncthreads();
    }
    float L = red[0];
    __syncthreads();
    float acc = 0.0f;
    for (int c = 0; c < NCH; c++) acc += se[c] * pv[((size_t)b * NCH + c) * DM + tid];
    r[b * DM + tid] = acc / L;
}

// ---------------- LayerNorm (residual broadcast) ----------------

// out16 = LN(x16 + r[b])
__global__ __launch_bounds__(256) void ln_bcast_kernel(const unsigned short* __restrict__ x16,
                                                       const float* __restrict__ r,
                                                       const float* __restrict__ g,
                                                       const float* __restrict__ bt,
                                                       unsigned short* __restrict__ out16) {
    int l = threadIdx.x & 63, w = threadIdx.x >> 6;
    int row = blockIdx.x * 4 + w;
    int b = row / NN;
    ushort4 xb = *(const ushort4*)&x16[(size_t)row * DM + l * 4];
    float4 rv = *(const float4*)(r + (size_t)b * DM + l * 4);
    float4 y;
    y.x = bf2f(xb.x) + rv.x; y.y = bf2f(xb.y) + rv.y;
    y.z = bf2f(xb.z) + rv.z; y.w = bf2f(xb.w) + rv.w;
    float s = y.x + y.y + y.z + y.w;
    float sq = y.x * y.x + y.y * y.y + y.z * y.z + y.w * y.w;
    s = waveAllReduce(s);
    sq = waveAllReduce(sq);
    float mean = s * (1.0f / 256.0f);
    float var = sq * (1.0f / 256.0f) - mean * mean;
    float rstd = rsqrtf(var + LN_EPS);
    float4 gv = *(const float4*)(g + l * 4);
    float4 bv = *(const float4*)(bt + l * 4);
    ushort4 o;
    o.x = f2bf((y.x - mean) * rstd * gv.x + bv.x);
    o.y = f2bf((y.y - mean) * rstd * gv.y + bv.y);
    o.z = f2bf((y.z - mean) * rstd * gv.z + bv.z);
    o.w = f2bf((y.w - mean) * rstd * gv.w + bv.w);
    *(ushort4*)&out16[(size_t)row * DM + l * 4] = o;
}

// ---------------- final projection ----------------

// partial column sums (no atomics): pcol[(b*100+c)*DM + d]
__global__ __launch_bounds__(256) void colsum_kernel(const unsigned short* __restrict__ x16,
                                                     float* __restrict__ pcol) {
    int b = blockIdx.y, c = blockIdx.x, d = threadIdx.x;
    int n0 = c * CCH, n1 = n0 + CCH;
    float acc = 0.0f;
    for (int n = n0; n < n1; n++) acc += bf2f(x16[((size_t)b * NN + n) * DM + d]);
    pcol[((size_t)b * (NN / CCH) + c) * DM + d] = acc;
}

__global__ __launch_bounds__(256) void final_kernel(const float* __restrict__ pcol,
                                                    const float* __restrict__ fcW,
                                                    const float* __restrict__ fcb,
                                                    float* __restrict__ out) {
    int b = blockIdx.x, d = threadIdx.x;
    __shared__ float sx[DM];
    float acc = 0.0f;
    for (int c = 0; c < NN / CCH; c++) acc += pcol[((size_t)b * (NN / CCH) + c) * DM + d];
    sx[d] = acc;
    __syncthreads();
    if (d < 10) {
        float o = 0.0f;
        for (int k = 0; k < DM; k++) o += sx[k] * fcW[k * 10 + d];
        out[b * 10 + d] = o * (1.0f / NN) + fcb[d];
    }
}

// ---------------- launch ----------------

extern "C" void kernel_launch(void* const* d_in, const int* in_sizes, int n_in,
                              void* d_out, int out_size, void* d_ws, size_t ws_size,
                              hipStream_t stream) {
    const float* x_in    = (const float*)d_in[0];
    const int*   src     = (const int*)d_in[1];
    const int*   dst     = (const int*)d_in[2];
    const float* W_conv0 = (const float*)d_in[3];
    const float* b_conv0 = (const float*)d_in[4];
    const float* W_convs = (const float*)d_in[5];
    const float* b_convs = (const float*)d_in[6];
    const float* mW1 = (const float*)d_in[7];
    const float* mb1 = (const float*)d_in[8];
    const float* mW2 = (const float*)d_in[9];
    const float* mb2 = (const float*)d_in[10];
    const float* mW3 = (const float*)d_in[11];
    const float* mb3 = (const float*)d_in[12];
    const float* ln1_g = (const float*)d_in[13];
    const float* ln1_b = (const float*)d_in[14];
    const float* ln2_g = (const float*)d_in[15];
    const float* ln2_b = (const float*)d_in[16];
    const float* attnW = (const float*)d_in[17];
    const float* attnu = (const float*)d_in[18];
    const float* fW1 = (const float*)d_in[19];
    const float* fb1 = (const float*)d_in[20];
    const float* fW2 = (const float*)d_in[21];
    const float* fb2 = (const float*)d_in[22];
    const float* fcW = (const float*)d_in[23];
    const float* fcb = (const float*)d_in[24];
    float* out = (float*)d_out;

    // ---- workspace carve ----
    char* p = (char*)d_ws;
    auto alloc = [&](size_t bytes) { char* q = p; p += (bytes + 255) & ~(size_t)255; return q; };
    unsigned short* sup16 = (unsigned short*)alloc((size_t)MR * DM * 2);  // node-major sup / h1
    unsigned short* act16 = (unsigned short*)alloc((size_t)MR * DM * 2);  // x bf16
    unsigned short* b16   = (unsigned short*)alloc((size_t)MR * DM * 2);  // LN1 output
    unsigned short* t1    = (unsigned short*)alloc((size_t)MR * 128 * 2); // x_in bf16 / MLP mid
    unsigned short* t2    = (unsigned short*)alloc((size_t)MR * 64 * 2);
    unsigned short* wt    = (unsigned short*)alloc((size_t)548864 * 2);
    float* rbuf = (float*)alloc(NB * DM * 4);
    float* pm0  = (float*)alloc(NB * NCH * 4);
    float* pl0  = (float*)alloc(NB * NCH * 4);
    float* pv0  = (float*)alloc((size_t)NB * NCH * DM * 4);
    float* pcol = (float*)alloc((size_t)NB * (NN / CCH) * DM * 4);
    int* counts   = (int*)alloc(NN * 4);
    int* row_ptr  = (int*)alloc((NN + 1) * 4);
    int* fill_pos = (int*)alloc(NN * 4);
    int* csr_boff = (int*)alloc(NE * 4);

    unsigned short* Wt_conv0 = wt;                       // 256x128
    unsigned short* Wt_convs = Wt_conv0 + 32768;         // 3 x 256x256
    unsigned short* mW1t = Wt_convs + 196608;            // 128x256
    unsigned short* mW2t = mW1t + 32768;                 // 64x128
    unsigned short* mW3t = mW2t + 8192;                  // 256x64
    unsigned short* fW1t = mW3t + 16384;                 // 2 x 256x256
    unsigned short* fW2t = fW1t + 131072;                // 2 x 256x256

    const dim3 blk(256);

    // ---- CSR build (by dst) ----
    zero_i32_kernel<<<(NN + 255) / 256, blk, 0, stream>>>(counts, NN);
    hist_kernel<<<(NE + 255) / 256, blk, 0, stream>>>(dst, counts, NE);
    scan_kernel<<<1, blk, 0, stream>>>(counts, row_ptr, fill_pos, NN);
    fill_kernel<<<(NE + 255) / 256, blk, 0, stream>>>(src, dst, fill_pos, csr_boff, NE);

    // ---- weight transposes ----
    TDs tds;
    tds.d[0]  = {W_conv0, Wt_conv0, 128, 256};
    tds.d[1]  = {W_convs + 0 * 65536, Wt_convs + 0 * 65536, 256, 256};
    tds.d[2]  = {W_convs + 1 * 65536, Wt_convs + 1 * 65536, 256, 256};
    tds.d[3]  = {W_convs + 2 * 65536, Wt_convs + 2 * 65536, 256, 256};
    tds.d[4]  = {mW1, mW1t, 256, 128};
    tds.d[5]  = {mW2, mW2t, 128, 64};
    tds.d[6]  = {mW3, mW3t, 64, 256};
    tds.d[7]  = {fW1 + 0 * 65536, fW1t + 0 * 65536, 256, 256};
    tds.d[8]  = {fW1 + 1 * 65536, fW1t + 1 * 65536, 256, 256};
    tds.d[9]  = {fW2 + 0 * 65536, fW2t + 0 * 65536, 256, 256};
    tds.d[10] = {fW2 + 1 * 65536, fW2t + 1 * 65536, 256, 256};
    transpose_all_kernel<<<dim3(256, 11), blk, 0, stream>>>(tds);

    cvt_bf16_kernel<<<(MR * 128 + 255) / 256, blk, 0, stream>>>(x_in, t1, MR * 128);

    // ---- GCN layers (GEMM writes node-major sup16; agg emits row-major bf16) ----
    mfma_gemm_kernel<256, 2, 128><<<dim3(1, MR / 64), blk, 0, stream>>>(t1, Wt_conv0, nullptr, sup16, 256, 0);
    agg_kernel<<<NN * 2, blk, 0, stream>>>(sup16, row_ptr, csr_boff, b_conv0, act16);
    for (int i = 0; i < 3; i++) {
        mfma_gemm_kernel<256, 2, 256><<<dim3(1, MR / 64), blk, 0, stream>>>(act16, Wt_convs + (size_t)i * 65536, nullptr, sup16, 256, 0);
        agg_kernel<<<NN * 2, blk, 0, stream>>>(sup16, row_ptr, csr_boff, b_convs + (size_t)i * 256, act16);
    }

    // ---- MLP ----
    mfma_gemm_kernel<128, 1, 256><<<dim3(1, MR / 64), blk, 0, stream>>>(act16, mW1t, mb1, t1, 128, 1);
    mfma_gemm_kernel<64, 1, 128><<<dim3(1, MR / 64), blk, 0, stream>>>(t1, mW2t, mb2, t2, 64, 1);
    mfma_gemm_kernel<256, 1, 64><<<dim3(1, MR / 64), blk, 0, stream>>>(t2, mW3t, mb3, act16, 256, 0);

    // ---- 2 attention/FFN blocks; x bf16 in act16 ----
    const dim3 poolGrid(NCH, NB);
    for (int i = 0; i < 2; i++) {
        const float* Wp = attnW + (size_t)i * DM * 8;
        const float* up = attnu + (size_t)i * 8;
        attn_pool_kernel<0><<<poolGrid, blk, 0, stream>>>(act16, Wp, up, nullptr, pm0, pl0, pv0);
        attn_combine_kernel<<<NB, blk, 0, stream>>>(pm0, pl0, pv0, rbuf);
        for (int it = 0; it < 3; it++) {
            attn_pool_kernel<1><<<poolGrid, blk, 0, stream>>>(act16, nullptr, nullptr, rbuf, pm0, pl0, pv0);
            attn_combine_kernel<<<NB, blk, 0, stream>>>(pm0, pl0, pv0, rbuf);
        }
        // x1 = LN(x + r) -> b16
        ln_bcast_kernel<<<MR / 4, blk, 0, stream>>>(act16, rbuf, ln1_g + (size_t)i * DM,
                                                    ln1_b + (size_t)i * DM, b16);
        // h1 = relu(x1 @ fW1 + fb1) -> sup16 (row-major bf16)
        mfma_gemm_kernel<256, 1, 256><<<dim3(1, MR / 64), blk, 0, stream>>>(b16, fW1t + (size_t)i * 65536,
                                                                            fb1 + (size_t)i * DM, sup16, 256, 1);
        // x = LN(x1 + (h1 @ fW2 + fb2)) -> act16  (fused GEMM+residual+LN)
        gemm_ln_kernel<<<MR / 64, blk, 0, stream>>>(sup16, fW2t + (size_t)i * 65536,
                                                    fb2 + (size_t)i * DM, b16,
                                                    ln2_g + (size_t)i * DM, ln2_b + (size_t)i * DM,
                                                    act16);
    }

    // ---- final: mean over nodes commutes with the linear layer ----
    colsum_kernel<<<dim3(NN / CCH, NB), blk, 0, stream>>>(act16, pcol);
    final_kernel<<<NB, blk, 0, stream>>>(pcol, fcW, fcb, out);
}